// Round 3
// baseline (632.146 us; speedup 1.0000x reference)
//
#include <hip/hip_runtime.h>
#include <hip/hip_bf16.h>
#include <math.h>

#define NQ    12
#define DIM   4096        // 2^NQ
#define NSAMP 2048
#define NLAY  3
#define NBLK  16          // 2048 / 128
#define NPART (NBLK*NBLK) // 256 partial slots
#define BK    16

// ---------------------------------------------------------------------------
// Kernel 1: simulate the 12-qubit circuit for one sample per block.
// State lives in LDS (4096 floats). Bit q of the flat index = qubit q.
// (Any fixed qubit->bit mapping gives a global permutation of amplitudes,
//  identical for all samples; inner products are invariant, and the CZ ring
//  edge set {q,q+1 mod 12} maps to itself.)
// ---------------------------------------------------------------------------
__global__ __launch_bounds__(256) void sim_kernel(const float* __restrict__ data,
                                                  const float* __restrict__ params,
                                                  float* __restrict__ psi)
{
    __shared__ float st[DIM];
    __shared__ float cs[NLAY*NQ], sn[NLAY*NQ];
    const int tid = threadIdx.x;
    const int smp = blockIdx.x;

    if (tid < NLAY*NQ) {
        const int q = tid % NQ;
        const float th = 0.5f * (params[tid] + data[smp*NQ + q]);
        cs[tid] = cosf(th);
        sn[tid] = sinf(th);
    }
    #pragma unroll
    for (int u = 0; u < DIM/256; ++u) st[tid + u*256] = 0.0f;
    if (tid == 0) st[0] = 1.0f;   // tid 0 zeroed st[0] itself; program order ok
    __syncthreads();

    for (int l = 0; l < NLAY; ++l) {
        for (int q = 0; q < NQ; ++q) {
            const float c = cs[l*NQ + q], s = sn[l*NQ + q];
            const int m = 1 << q;
            #pragma unroll
            for (int u = 0; u < DIM/2/256; ++u) {
                const int p  = tid + u*256;
                const int i0 = ((p & ~(m-1)) << 1) | (p & (m-1));
                const int i1 = i0 | m;
                const float a0 = st[i0], a1 = st[i1];
                st[i0] = c*a0 - s*a1;
                st[i1] = s*a0 + c*a1;
            }
            __syncthreads();
        }
        // CZ ring: flip sign where an odd number of edges (q,q+1 mod 12)
        // have both bits set.
        #pragma unroll
        for (int u = 0; u < DIM/256; ++u) {
            const int i = tid + u*256;
            const int y = (i >> 1) | ((i & 1) << (NQ-1));
            if (__popc(i & y) & 1) st[i] = -st[i];
        }
        __syncthreads();
    }
    #pragma unroll
    for (int u = 0; u < DIM/256; ++u) {
        const int i = tid + u*256;
        psi[(size_t)smp*DIM + i] = st[i];
    }
}

// ---------------------------------------------------------------------------
// Kernel 2: fused Gram + reduction.  Block (bj,bi) computes the 128x128 tile
// G[bi*128..][bj*128..] = Psi_rows . Psi_rows^T and immediately reduces
// s1 += l_i l_j G^2, s2 += G^4 into per-block double partials.
// ---------------------------------------------------------------------------
__global__ __launch_bounds__(256) void gram_kernel(const float* __restrict__ psi,
                                                   const int* __restrict__ labels,
                                                   double* __restrict__ part1,
                                                   double* __restrict__ part2)
{
    // Tiles stored transposed [k][m], leading dim 132: staging writes 2-way
    // bank aliasing (free), inner-loop float4 reads 2-way (free).
    __shared__ __align__(16) float As[BK][132];
    __shared__ __align__(16) float Bs[BK][132];
    __shared__ double red[256];

    const int tid = threadIdx.x;
    const int tx = tid & 15, ty = tid >> 4;
    const int bi = blockIdx.y, bj = blockIdx.x;
    const float* __restrict__ Abase = psi + (size_t)bi * 128 * DIM;
    const float* __restrict__ Bbase = psi + (size_t)bj * 128 * DIM;

    float acc[8][8];
    #pragma unroll
    for (int i = 0; i < 8; ++i)
        #pragma unroll
        for (int j = 0; j < 8; ++j) acc[i][j] = 0.0f;

    const int row0 = tid >> 2;        // 0..63
    const int row1 = row0 + 64;       // 64..127
    const int kq4  = (tid & 3) * 4;   // 0,4,8,12

    for (int kk = 0; kk < DIM; kk += BK) {
        const float4 a0 = *(const float4*)(Abase + (size_t)row0*DIM + kk + kq4);
        const float4 a1 = *(const float4*)(Abase + (size_t)row1*DIM + kk + kq4);
        const float4 b0 = *(const float4*)(Bbase + (size_t)row0*DIM + kk + kq4);
        const float4 b1 = *(const float4*)(Bbase + (size_t)row1*DIM + kk + kq4);
        As[kq4+0][row0] = a0.x; As[kq4+1][row0] = a0.y; As[kq4+2][row0] = a0.z; As[kq4+3][row0] = a0.w;
        As[kq4+0][row1] = a1.x; As[kq4+1][row1] = a1.y; As[kq4+2][row1] = a1.z; As[kq4+3][row1] = a1.w;
        Bs[kq4+0][row0] = b0.x; Bs[kq4+1][row0] = b0.y; Bs[kq4+2][row0] = b0.z; Bs[kq4+3][row0] = b0.w;
        Bs[kq4+0][row1] = b1.x; Bs[kq4+1][row1] = b1.y; Bs[kq4+2][row1] = b1.z; Bs[kq4+3][row1] = b1.w;
        __syncthreads();
        #pragma unroll
        for (int k = 0; k < BK; ++k) {
            float av[8], bv[8];
            *(float4*)&av[0] = *(const float4*)&As[k][ty*4];
            *(float4*)&av[4] = *(const float4*)&As[k][64 + ty*4];
            *(float4*)&bv[0] = *(const float4*)&Bs[k][tx*4];
            *(float4*)&bv[4] = *(const float4*)&Bs[k][64 + tx*4];
            #pragma unroll
            for (int i = 0; i < 8; ++i)
                #pragma unroll
                for (int j = 0; j < 8; ++j)
                    acc[i][j] += av[i] * bv[j];
        }
        __syncthreads();
    }

    // rows/cols this thread owns: {ty*4+i, 64+ty*4+i} x {tx*4+j, 64+tx*4+j}
    float lr[8], lc[8];
    const int rbase = bi*128, cbase = bj*128;
    #pragma unroll
    for (int i = 0; i < 4; ++i) {
        lr[i]   = 2.0f*(float)labels[rbase +      ty*4 + i] - 1.0f;
        lr[i+4] = 2.0f*(float)labels[rbase + 64 + ty*4 + i] - 1.0f;
        lc[i]   = 2.0f*(float)labels[cbase +      tx*4 + i] - 1.0f;
        lc[i+4] = 2.0f*(float)labels[cbase + 64 + tx*4 + i] - 1.0f;
    }
    double s1 = 0.0, s2 = 0.0;
    #pragma unroll
    for (int i = 0; i < 8; ++i)
        #pragma unroll
        for (int j = 0; j < 8; ++j) {
            const float g  = acc[i][j];
            const float g2 = g*g;
            s1 += (double)(lr[i]*lc[j]*g2);
            const double d = (double)g2;
            s2 += d*d;
        }

    red[tid] = s1; __syncthreads();
    for (int off = 128; off; off >>= 1) { if (tid < off) red[tid] += red[tid+off]; __syncthreads(); }
    if (tid == 0) part1[bi*NBLK + bj] = red[0];
    __syncthreads();
    red[tid] = s2; __syncthreads();
    for (int off = 128; off; off >>= 1) { if (tid < off) red[tid] += red[tid+off]; __syncthreads(); }
    if (tid == 0) part2[bi*NBLK + bj] = red[0];
}

// ---------------------------------------------------------------------------
// Kernel 3: final reduce of 256 partials -> scalar float32 output.
// square_sum_l = N^2 exactly (l_i^2 = 1), so out = s1 / (N * sqrt(s2)).
// ---------------------------------------------------------------------------
__global__ __launch_bounds__(256) void finalize_kernel(const double* __restrict__ part1,
                                                       const double* __restrict__ part2,
                                                       float* __restrict__ out)
{
    __shared__ double r1[256], r2[256];
    const int tid = threadIdx.x;
    r1[tid] = part1[tid];
    r2[tid] = part2[tid];
    __syncthreads();
    for (int off = 128; off; off >>= 1) {
        if (tid < off) { r1[tid] += r1[tid+off]; r2[tid] += r2[tid+off]; }
        __syncthreads();
    }
    if (tid == 0) {
        const double res = r1[0] / (sqrt(r2[0]) * (double)NSAMP);
        out[0] = (float)res;
    }
}

// ---------------------------------------------------------------------------
extern "C" void kernel_launch(void* const* d_in, const int* in_sizes, int n_in,
                              void* d_out, int out_size, void* d_ws, size_t ws_size,
                              hipStream_t stream)
{
    const float* data   = (const float*)d_in[0]; // (2048,12) float32
    const int*   labels = (const int*)d_in[1];   // (2048,)   int32
    const float* params = (const float*)d_in[2]; // (3,12)    float32

    double* part1 = (double*)d_ws;              // 256 doubles
    double* part2 = part1 + NPART;              // 256 doubles
    float*  psi   = (float*)((char*)d_ws + 8192); // 2048*4096 fp32 = 32 MiB

    sim_kernel<<<NSAMP, 256, 0, stream>>>(data, params, psi);
    gram_kernel<<<dim3(NBLK, NBLK), 256, 0, stream>>>(psi, labels, part1, part2);
    finalize_kernel<<<1, 256, 0, stream>>>(part1, part2, (float*)d_out);
}

// Round 4
// 262.816 us; speedup vs baseline: 2.4053x; 2.4053x over previous
//
#include <hip/hip_runtime.h>
#include <math.h>

#define NQ    12
#define DIM   4096        // 2^NQ
#define NSAMP 2048
#define NLAY  3
#define TILE  64
#define NT    32          // 2048/64 tiles per dimension
#define BK    64
#define LDK   72          // padded LDS row stride in ushort (144 B = 36 banks)

typedef __attribute__((ext_vector_type(8))) short bf16x8;   // 8 bf16 = 4 VGPRs
typedef __attribute__((ext_vector_type(4))) float floatx4;  // MFMA 16x16 acc

__device__ __forceinline__ unsigned short f32_to_bf16(float x) {
    unsigned u = __builtin_bit_cast(unsigned, x);
    u += 0x7FFFu + ((u >> 16) & 1u);            // round-to-nearest-even
    return (unsigned short)(u >> 16);
}
__device__ __forceinline__ float bf16_to_f32(unsigned short h) {
    unsigned u = (unsigned)h << 16;
    return __builtin_bit_cast(float, u);
}

// ---------------------------------------------------------------------------
// Kernel 1: 12-qubit circuit per sample, state in LDS.  Emits psi as a
// bf16 split pair: psi = hi + lo (lo = bf16(psi - hi)).
// Qubit->bit mapping is a fixed global permutation: inner products invariant,
// CZ ring edge set maps to itself.
// ---------------------------------------------------------------------------
__global__ __launch_bounds__(256) void sim_kernel(const float* __restrict__ data,
                                                  const float* __restrict__ params,
                                                  unsigned short* __restrict__ psi_hi,
                                                  unsigned short* __restrict__ psi_lo)
{
    __shared__ float st[DIM];
    __shared__ float cs[NLAY*NQ], sn[NLAY*NQ];
    const int tid = threadIdx.x;
    const int smp = blockIdx.x;

    if (tid < NLAY*NQ) {
        const int q = tid % NQ;
        const float th = 0.5f * (params[tid] + data[smp*NQ + q]);
        cs[tid] = cosf(th);
        sn[tid] = sinf(th);
    }
    #pragma unroll
    for (int u = 0; u < DIM/256; ++u) st[tid + u*256] = 0.0f;
    if (tid == 0) st[0] = 1.0f;
    __syncthreads();

    for (int l = 0; l < NLAY; ++l) {
        for (int q = 0; q < NQ; ++q) {
            const float c = cs[l*NQ + q], s = sn[l*NQ + q];
            const int m = 1 << q;
            #pragma unroll
            for (int u = 0; u < DIM/2/256; ++u) {
                const int p  = tid + u*256;
                const int i0 = ((p & ~(m-1)) << 1) | (p & (m-1));
                const int i1 = i0 | m;
                const float a0 = st[i0], a1 = st[i1];
                st[i0] = c*a0 - s*a1;
                st[i1] = s*a0 + c*a1;
            }
            __syncthreads();
        }
        #pragma unroll
        for (int u = 0; u < DIM/256; ++u) {
            const int i = tid + u*256;
            const int y = (i >> 1) | ((i & 1) << (NQ-1));
            if (__popc(i & y) & 1) st[i] = -st[i];
        }
        __syncthreads();
    }
    #pragma unroll
    for (int u = 0; u < DIM/256; ++u) {
        const int i = tid + u*256;
        const float x = st[i];
        const unsigned short hb = f32_to_bf16(x);
        const float lres = x - bf16_to_f32(hb);
        psi_hi[(size_t)smp*DIM + i] = hb;
        psi_lo[(size_t)smp*DIM + i] = f32_to_bf16(lres);
    }
}

// ---------------------------------------------------------------------------
// Kernel 2: MFMA split-bf16 Gram + fused reduction, triangular grid.
// Block (bi,bj), bj>=bi only: 64x64 tile of G = hi.hi^T + hi.lo^T + lo.hi^T,
// weight 2 off-diagonal (symmetry), reduce s1 += l_i l_j G^2, s2 += G^4.
// 4 waves, each a 32x32 sub-tile = 2x2 frags of mfma_f32_16x16x32_bf16.
// ---------------------------------------------------------------------------
__global__ __launch_bounds__(256) void gram_kernel(const unsigned short* __restrict__ ph,
                                                   const unsigned short* __restrict__ pl,
                                                   const int* __restrict__ labels,
                                                   double* __restrict__ part1,
                                                   double* __restrict__ part2)
{
    const int bi = blockIdx.y, bj = blockIdx.x;
    if (bj < bi) return;   // uniform per block, before any barrier

    __shared__ unsigned short Ah[TILE*LDK], Al[TILE*LDK];
    __shared__ unsigned short Bh[TILE*LDK], Bl[TILE*LDK];
    __shared__ float la[TILE], lb[TILE];
    __shared__ double red[256];

    const int tid = threadIdx.x;
    if (tid < 64)       la[tid]      = 2.0f*(float)labels[bi*64 + tid]      - 1.0f;
    else if (tid < 128) lb[tid - 64] = 2.0f*(float)labels[bj*64 + tid - 64] - 1.0f;

    const int wave = tid >> 6, lane = tid & 63;
    const int wr = wave >> 1, wc = wave & 1;      // 32x32 sub-tile coords
    const int m_lo = lane & 15, kq = lane >> 4;   // MFMA A/B operand lane map

    floatx4 acc[2][2];
    #pragma unroll
    for (int i = 0; i < 2; ++i)
        #pragma unroll
        for (int j = 0; j < 2; ++j) acc[i][j] = (floatx4){0.f,0.f,0.f,0.f};

    // staging map: thread -> (row sr, 16B chunk sc); rows sr and sr+32
    const int sr = tid >> 3;   // 0..31
    const int sc = tid & 7;    // 0..7
    const size_t arow0 = (size_t)bi * 64, brow0 = (size_t)bj * 64;

    for (int kk = 0; kk < DIM; kk += BK) {
        const size_t ga0 = (arow0 + sr)      * DIM + kk + sc*8;
        const size_t ga1 = (arow0 + sr + 32) * DIM + kk + sc*8;
        const size_t gb0 = (brow0 + sr)      * DIM + kk + sc*8;
        const size_t gb1 = (brow0 + sr + 32) * DIM + kk + sc*8;
        const uint4 vah0 = *(const uint4*)(ph + ga0);
        const uint4 vah1 = *(const uint4*)(ph + ga1);
        const uint4 val0 = *(const uint4*)(pl + ga0);
        const uint4 val1 = *(const uint4*)(pl + ga1);
        const uint4 vbh0 = *(const uint4*)(ph + gb0);
        const uint4 vbh1 = *(const uint4*)(ph + gb1);
        const uint4 vbl0 = *(const uint4*)(pl + gb0);
        const uint4 vbl1 = *(const uint4*)(pl + gb1);
        __syncthreads();   // previous iter's LDS reads complete
        *(uint4*)&Ah[ sr      *LDK + sc*8] = vah0;
        *(uint4*)&Ah[(sr + 32)*LDK + sc*8] = vah1;
        *(uint4*)&Al[ sr      *LDK + sc*8] = val0;
        *(uint4*)&Al[(sr + 32)*LDK + sc*8] = val1;
        *(uint4*)&Bh[ sr      *LDK + sc*8] = vbh0;
        *(uint4*)&Bh[(sr + 32)*LDK + sc*8] = vbh1;
        *(uint4*)&Bl[ sr      *LDK + sc*8] = vbl0;
        *(uint4*)&Bl[(sr + 32)*LDK + sc*8] = vbl1;
        __syncthreads();

        #pragma unroll
        for (int ks = 0; ks < 2; ++ks) {
            const int ko = ks*32 + kq*8;
            // A/B operand layout (m89/m120): lane holds M[row=lane&15][k=kq*8+j]
            const bf16x8 a_h0 = *(const bf16x8*)&Ah[(wr*32 +  0 + m_lo)*LDK + ko];
            const bf16x8 a_h1 = *(const bf16x8*)&Ah[(wr*32 + 16 + m_lo)*LDK + ko];
            const bf16x8 a_l0 = *(const bf16x8*)&Al[(wr*32 +  0 + m_lo)*LDK + ko];
            const bf16x8 a_l1 = *(const bf16x8*)&Al[(wr*32 + 16 + m_lo)*LDK + ko];
            const bf16x8 b_h0 = *(const bf16x8*)&Bh[(wc*32 +  0 + m_lo)*LDK + ko];
            const bf16x8 b_h1 = *(const bf16x8*)&Bh[(wc*32 + 16 + m_lo)*LDK + ko];
            const bf16x8 b_l0 = *(const bf16x8*)&Bl[(wc*32 +  0 + m_lo)*LDK + ko];
            const bf16x8 b_l1 = *(const bf16x8*)&Bl[(wc*32 + 16 + m_lo)*LDK + ko];

            acc[0][0] = __builtin_amdgcn_mfma_f32_16x16x32_bf16(a_h0, b_h0, acc[0][0], 0, 0, 0);
            acc[0][1] = __builtin_amdgcn_mfma_f32_16x16x32_bf16(a_h0, b_h1, acc[0][1], 0, 0, 0);
            acc[1][0] = __builtin_amdgcn_mfma_f32_16x16x32_bf16(a_h1, b_h0, acc[1][0], 0, 0, 0);
            acc[1][1] = __builtin_amdgcn_mfma_f32_16x16x32_bf16(a_h1, b_h1, acc[1][1], 0, 0, 0);

            acc[0][0] = __builtin_amdgcn_mfma_f32_16x16x32_bf16(a_h0, b_l0, acc[0][0], 0, 0, 0);
            acc[0][1] = __builtin_amdgcn_mfma_f32_16x16x32_bf16(a_h0, b_l1, acc[0][1], 0, 0, 0);
            acc[1][0] = __builtin_amdgcn_mfma_f32_16x16x32_bf16(a_h1, b_l0, acc[1][0], 0, 0, 0);
            acc[1][1] = __builtin_amdgcn_mfma_f32_16x16x32_bf16(a_h1, b_l1, acc[1][1], 0, 0, 0);

            acc[0][0] = __builtin_amdgcn_mfma_f32_16x16x32_bf16(a_l0, b_h0, acc[0][0], 0, 0, 0);
            acc[0][1] = __builtin_amdgcn_mfma_f32_16x16x32_bf16(a_l0, b_h1, acc[0][1], 0, 0, 0);
            acc[1][0] = __builtin_amdgcn_mfma_f32_16x16x32_bf16(a_l1, b_h0, acc[1][0], 0, 0, 0);
            acc[1][1] = __builtin_amdgcn_mfma_f32_16x16x32_bf16(a_l1, b_h1, acc[1][1], 0, 0, 0);
        }
    }

    // Epilogue: C/D layout (m89): C[row=(lane>>4)*4+r][col=lane&15]
    double s1 = 0.0, s2 = 0.0;
    const int rq = (lane >> 4) * 4;
    const int cl = lane & 15;
    #pragma unroll
    for (int fi = 0; fi < 2; ++fi)
        #pragma unroll
        for (int fj = 0; fj < 2; ++fj)
            #pragma unroll
            for (int r = 0; r < 4; ++r) {
                const int row = wr*32 + fi*16 + rq + r;
                const int col = wc*32 + fj*16 + cl;
                const float g  = acc[fi][fj][r];
                const float g2 = g * g;
                s1 += (double)(la[row] * lb[col] * g2);
                const double d = (double)g2;
                s2 += d * d;
            }
    const double w = (bi == bj) ? 1.0 : 2.0;  // symmetry weight

    red[tid] = s1 * w; __syncthreads();
    for (int off = 128; off; off >>= 1) { if (tid < off) red[tid] += red[tid+off]; __syncthreads(); }
    if (tid == 0) part1[bi*NT + bj] = red[0];
    __syncthreads();
    red[tid] = s2 * w; __syncthreads();
    for (int off = 128; off; off >>= 1) { if (tid < off) red[tid] += red[tid+off]; __syncthreads(); }
    if (tid == 0) part2[bi*NT + bj] = red[0];
}

// ---------------------------------------------------------------------------
// Kernel 3: reduce upper-triangular partial slots -> scalar f32.
// square_sum_l = N^2 exactly, so out = s1 / (N * sqrt(s2)).
// Only slots with bj>=bi were written (ws is poison-filled) -> mask here.
// ---------------------------------------------------------------------------
__global__ __launch_bounds__(256) void finalize_kernel(const double* __restrict__ part1,
                                                       const double* __restrict__ part2,
                                                       float* __restrict__ out)
{
    __shared__ double r1[256], r2[256];
    const int tid = threadIdx.x;
    double a = 0.0, b = 0.0;
    #pragma unroll
    for (int u = 0; u < 4; ++u) {
        const int s  = tid + u*256;
        const int bi = s >> 5, bj = s & 31;
        if (bj >= bi) { a += part1[s]; b += part2[s]; }
    }
    r1[tid] = a; r2[tid] = b; __syncthreads();
    for (int off = 128; off; off >>= 1) {
        if (tid < off) { r1[tid] += r1[tid+off]; r2[tid] += r2[tid+off]; }
        __syncthreads();
    }
    if (tid == 0) out[0] = (float)(r1[0] / (sqrt(r2[0]) * (double)NSAMP));
}

// ---------------------------------------------------------------------------
extern "C" void kernel_launch(void* const* d_in, const int* in_sizes, int n_in,
                              void* d_out, int out_size, void* d_ws, size_t ws_size,
                              hipStream_t stream)
{
    const float* data   = (const float*)d_in[0]; // (2048,12) f32
    const int*   labels = (const int*)d_in[1];   // (2048,)   i32
    const float* params = (const float*)d_in[2]; // (3,12)    f32

    double* part1 = (double*)d_ws;                              // 1024 doubles
    double* part2 = part1 + NT*NT;                              // 1024 doubles
    unsigned short* psi_hi = (unsigned short*)((char*)d_ws + 16384);        // 16 MiB
    unsigned short* psi_lo = psi_hi + (size_t)NSAMP * DIM;                  // 16 MiB

    sim_kernel<<<NSAMP, 256, 0, stream>>>(data, params, psi_hi, psi_lo);
    gram_kernel<<<dim3(NT, NT), 256, 0, stream>>>(psi_hi, psi_lo, labels, part1, part2);
    finalize_kernel<<<1, 256, 0, stream>>>(part1, part2, (float*)d_out);
}